// Round 10
// baseline (343.696 us; speedup 1.0000x reference)
//
#include <hip/hip_runtime.h>
#include <stdint.h>

#define BB 2
#define SS 2048
#define DD 1024
#define HH 16
#define HDD 64

typedef _Float16 f16x8 __attribute__((ext_vector_type(8)));
typedef _Float16 f16x4 __attribute__((ext_vector_type(4)));
typedef float f32x4 __attribute__((ext_vector_type(4)));

#define MFMA16(a,b,c) __builtin_amdgcn_mfma_f32_16x16x32_f16((a),(b),(c),0,0,0)

__device__ __forceinline__ _Float16 toh(float v) { return (_Float16)v; }

// async global->LDS, 16B per lane; LDS dest is wave-uniform base + lane*16
__device__ __forceinline__ void gll16(const void* g, void* l) {
  __builtin_amdgcn_global_load_lds(
      (const __attribute__((address_space(1))) unsigned int*)g,
      (__attribute__((address_space(3))) unsigned int*)l, 16, 0, 0);
}

// ---------------- ws layout (f16 elements) — stays under 48 MiB ----------------
//   xb @0 (4194304) | wqb @4194304 | wkb @5242880 | wvb @6291456 | wob @7340032
//   Qw @8388608 [B,H,S,64] (pre-scaled 0.125*log2e) | Kw @12582912 | Vtw @16777216 [B,H,64,S]
//   attnb @20971520 [B,S,D]   (ends exactly at 25165824 f16 = 48 MiB)
//   mlb (f32, 65536) overlays wqb @4194304 (dead after k_gemm_qkv): rinv per row
__global__ __launch_bounds__(256) void k_convert(
    const float* __restrict__ x, const float* __restrict__ Wq, const float* __restrict__ Wk,
    const float* __restrict__ Wv, const float* __restrict__ Wo, _Float16* __restrict__ ws) {
  int i = blockIdx.x * 256 + threadIdx.x;
  const float4* src; _Float16* dst; int idx;
  if (i < 1048576) { src = (const float4*)x; dst = ws; idx = i; }
  else {
    int j = i - 1048576;
    int wsel = j >> 18;
    idx = j & 262143;
    src = (const float4*)(wsel == 0 ? Wq : wsel == 1 ? Wk : wsel == 2 ? Wv : Wo);
    dst = ws + 4194304 + (size_t)wsel * 1048576;
  }
  float4 f = src[idx];
  f16x4 o = { toh(f.x), toh(f.y), toh(f.z), toh(f.w) };
  *(f16x4*)(dst + (size_t)idx * 4) = o;
}

// ---------------- shared GEMM core: C[128x128] = A[128xK] * W[128xK]^T, K=1024 ----------
__device__ __forceinline__ void stage2(const _Float16* g, _Float16* lds, int t) {
#pragma unroll
  for (int i = 0; i < 2; ++i) {
    const _Float16* src = g + (size_t)(i * 64 + (t >> 2)) * 1024 + (t & 3) * 8;
    gll16(src, lds + i * 2048 + t * 8);
  }
}

__device__ __forceinline__ void gemm_core(const _Float16* __restrict__ A,
                                          const _Float16* __restrict__ W,
                                          int bm, int bn, _Float16* As, _Float16* Bs,
                                          f32x4 (&acc)[4][4]) {
  const int t = threadIdx.x;
  const int l = t & 63, w = t >> 6;
  const int wr = w >> 1, wc = w & 1, li = l & 15, lg = l >> 4;
  const _Float16* Abase = A + (size_t)bm * 128 * 1024;
  const _Float16* Wbase = W + (size_t)bn * 128 * 1024;

  stage2(Abase, As, t);
  stage2(Wbase, Bs, t);
  int cur = 0;
  for (int kt = 0; kt < 32; ++kt) {
    __syncthreads();
    if (kt < 31) {
      stage2(Abase + (kt + 1) * 32, As + (cur ^ 1) * 4096, t);
      stage2(Wbase + (kt + 1) * 32, Bs + (cur ^ 1) * 4096, t);
    }
    const _Float16* Ab = As + cur * 4096;
    const _Float16* Bb = Bs + cur * 4096;
    f16x8 af[4], bfr[4];
#pragma unroll
    for (int m = 0; m < 4; ++m)
      af[m] = *(const f16x8*)(Ab + (wr * 64 + m * 16 + li) * 32 + lg * 8);
#pragma unroll
    for (int n = 0; n < 4; ++n)
      bfr[n] = *(const f16x8*)(Bb + (wc * 64 + n * 16 + li) * 32 + lg * 8);
    __builtin_amdgcn_s_setprio(1);
#pragma unroll
    for (int m = 0; m < 4; ++m)
#pragma unroll
      for (int n = 0; n < 4; ++n)
        acc[m][n] = MFMA16(af[m], bfr[n], acc[m][n]);
    __builtin_amdgcn_s_setprio(0);
    cur ^= 1;
  }
}

// ---------------- K1: fused QKV projection ----------------
__global__ __launch_bounds__(256) void k_gemm_qkv(
    const _Float16* __restrict__ xb, const _Float16* __restrict__ wqb,
    const _Float16* __restrict__ wkb, const _Float16* __restrict__ wvb,
    const float* __restrict__ bq, const float* __restrict__ bk, const float* __restrict__ bv,
    _Float16* __restrict__ Qw, _Float16* __restrict__ Kw, _Float16* __restrict__ Vtw) {
  int mode = blockIdx.z;
  const _Float16* W = mode == 0 ? wqb : mode == 1 ? wkb : wvb;
  const float* bias = mode == 0 ? bq : mode == 1 ? bk : bv;
  __shared__ _Float16 As[8192], Bs[8192];
  f32x4 acc[4][4] = {};
  gemm_core(xb, W, blockIdx.y, blockIdx.x, As, Bs, acc);

  int t = threadIdx.x, l = t & 63, w = t >> 6, wr = w >> 1, wc = w & 1, li = l & 15, lg = l >> 4;
  int rb = blockIdx.y * 128 + wr * 64, cb = blockIdx.x * 128 + wc * 64;
  // fold 1/sqrt(HD) and log2(e) into Q so softmax exp becomes exp2
  float scale = (mode == 0) ? 0.125f * 1.4426950408889634f : 1.0f;
#pragma unroll
  for (int n = 0; n < 4; ++n) {
    int col = cb + n * 16 + li;
    float bsv = bias[col];
    int hh = col >> 6, hd = col & 63;
#pragma unroll
    for (int m = 0; m < 4; ++m)
#pragma unroll
      for (int r = 0; r < 4; ++r) {
        int row = rb + m * 16 + lg * 4 + r;
        int bb = row >> 11, ssi = row & 2047;
        float val = (acc[m][n][r] + bsv) * scale;
        if (mode == 0)
          Qw[((size_t)(bb * HH + hh) * SS + ssi) * HDD + hd] = toh(val);
        else if (mode == 1)
          Kw[((size_t)(bb * HH + hh) * SS + ssi) * HDD + hd] = toh(val);
        else
          Vtw[((size_t)(bb * HH + hh) * HDD + hd) * SS + ssi] = toh(val);
      }
  }
}

// ---------------- K2a: flash pass — rinv and attnb ----------------
// R7 skeleton but: V fragments prefetched into REGISTERS at iteration start
// (issue-early/consume-late; V is L2-resident per head) instead of LDS staging.
// LDS 50->25 KB; 64 q-rows/block -> 1024 blocks -> 4 blocks/CU (16 waves/CU).
// K stays LDS-double-buffered (the prefetch R6 proved essential).
__global__ __launch_bounds__(256, 4) void k_flash(
    const _Float16* __restrict__ Qw, const _Float16* __restrict__ Kw,
    const _Float16* __restrict__ Vtw, float* __restrict__ mlb, _Float16* __restrict__ attnb) {
  int qb = blockIdx.x;            // 0..31 (64 rows per block, 16 per wave)
  int h = blockIdx.y, b = blockIdx.z;
  int t = threadIdx.x, l = t & 63, w = t >> 6;
  int li = l & 15, lg = l >> 4;
  size_t bh = (size_t)(b * HH + h);
  const _Float16* Qh = Qw + bh * SS * HDD;
  const _Float16* Kh = Kw + bh * SS * HDD;
  const _Float16* Vh = Vtw + bh * HDD * SS;
  int qrow = qb * 64 + w * 16;

  __shared__ _Float16 Kbuf[2][4096];
  __shared__ _Float16 Wl[4][16][72];   // per-wave P transpose (+8 pad)

  f16x8 aq0 = *(const f16x8*)&Qh[(size_t)(qrow + li) * HDD + lg * 8];
  f16x8 aq1 = *(const f16x8*)&Qh[(size_t)(qrow + li) * HDD + 32 + lg * 8];

  const f32x4 fzero = {0.f, 0.f, 0.f, 0.f};
  f32x4 oacc[4] = {fzero, fzero, fzero, fzero};
  float lsum[4] = {0.f, 0.f, 0.f, 0.f};

  auto STAGE = [&](int kt, int sel) {
    int kb = kt * 64;
#pragma unroll
    for (int c2 = 0; c2 < 2; ++c2) {
      int s = c2 * 256 + t;
      int row = s >> 3, cc = (s & 7) ^ (row & 7);
      gll16(Kh + (size_t)(kb + row) * HDD + cc * 8, (void*)&Kbuf[sel][s * 8]);
    }
  };

  STAGE(0, 0);
  __syncthreads();
  int cur = 0;
  for (int kt = 0; kt < 32; ++kt) {
    int kb = kt * 64;
    // early V register prefetch (consumed in PV below; QK+exp hides L2 latency)
    f16x8 v0[4], v1[4];
#pragma unroll
    for (int n = 0; n < 4; ++n) {
      const _Float16* vp = &Vh[(size_t)(n * 16 + li) * SS + kb + lg * 8];
      v0[n] = *(const f16x8*)vp;
      v1[n] = *(const f16x8*)(vp + 32);
    }
    if (kt < 31) STAGE(kt + 1, cur ^ 1);
    const _Float16* Kb = Kbuf[cur];
    f32x4 sf[4];
    __builtin_amdgcn_s_setprio(1);
#pragma unroll
    for (int f = 0; f < 4; ++f) {
      int row = f * 16 + li;
      f16x8 k0 = *(const f16x8*)(Kb + row * 64 + ((lg ^ (row & 7)) * 8));
      f16x8 k1 = *(const f16x8*)(Kb + row * 64 + (((lg + 4) ^ (row & 7)) * 8));
      f32x4 a = MFMA16(aq0, k0, fzero);
      sf[f] = MFMA16(aq1, k1, a);
    }
    __builtin_amdgcn_s_setprio(0);
#pragma unroll
    for (int f = 0; f < 4; ++f)
#pragma unroll
      for (int r = 0; r < 4; ++r) {
        float p = exp2f(sf[f][r]);
        lsum[r] += p;
        Wl[w][lg * 4 + r][f * 16 + li] = toh(p);
      }
    // PV: A = P (per-wave LDS transpose; lgkmcnt orders within wave), B = V regs
    f16x8 aw0 = *(const f16x8*)&Wl[w][li][lg * 8];
    f16x8 aw1 = *(const f16x8*)&Wl[w][li][32 + lg * 8];
    __builtin_amdgcn_s_setprio(1);
#pragma unroll
    for (int n = 0; n < 4; ++n) {
      oacc[n] = MFMA16(aw0, v0[n], oacc[n]);
      oacc[n] = MFMA16(aw1, v1[n], oacc[n]);
    }
    __builtin_amdgcn_s_setprio(0);
    __syncthreads();
    cur ^= 1;
  }

  // deferred row-sum reduce (within 16-lane groups)
#pragma unroll
  for (int d = 1; d < 16; d <<= 1)
#pragma unroll
    for (int r = 0; r < 4; ++r) lsum[r] += __shfl_xor(lsum[r], d);
  float rinv[4];
#pragma unroll
  for (int r = 0; r < 4; ++r) rinv[r] = 1.0f / lsum[r];

#pragma unroll
  for (int n = 0; n < 4; ++n)
#pragma unroll
    for (int r = 0; r < 4; ++r) {
      int q = qrow + lg * 4 + r;
      attnb[((size_t)b * SS + q) * DD + h * 64 + n * 16 + li] = toh(oacc[n][r] * rinv[r]);
    }
  if (li == 0) {
#pragma unroll
    for (int r = 0; r < 4; ++r) {
      int q = qrow + lg * 4 + r;
      mlb[bh * SS + q] = rinv[r];
    }
  }
}

// ---------------- K2b: weights writer — independent 128x128 score tiles ----------------
__global__ __launch_bounds__(256) void k_wts(
    const _Float16* __restrict__ Qw, const _Float16* __restrict__ Kw,
    const float* __restrict__ mlb, float* __restrict__ wts) {
  int ktile = blockIdx.x, qtile = blockIdx.y;
  size_t bh = blockIdx.z;
  const _Float16* Qh = Qw + bh * SS * HDD;
  const _Float16* Kh = Kw + bh * SS * HDD;
  __shared__ _Float16 As[8192], Bs[8192];   // [128 rows][64], src-swizzled
  int t = threadIdx.x, l = t & 63, w = t >> 6, wr = w >> 1, wc = w & 1, li = l & 15, lg = l >> 4;

#pragma unroll
  for (int c4 = 0; c4 < 4; ++c4) {
    int s = c4 * 256 + t;
    int row = s >> 3, cc = (s & 7) ^ (row & 7);
    gll16(Qh + (size_t)(qtile * 128 + row) * HDD + cc * 8, (void*)&As[s * 8]);
    gll16(Kh + (size_t)(ktile * 128 + row) * HDD + cc * 8, (void*)&Bs[s * 8]);
  }
  __syncthreads();

  f32x4 acc[4][4] = {};
#pragma unroll
  for (int s = 0; s < 2; ++s) {
    f16x8 af[4], bf[4];
#pragma unroll
    for (int m = 0; m < 4; ++m) {
      int row = wr * 64 + m * 16 + li;
      af[m] = *(const f16x8*)(As + row * 64 + (((s * 4 + lg) ^ (row & 7)) * 8));
    }
#pragma unroll
    for (int n = 0; n < 4; ++n) {
      int row = wc * 64 + n * 16 + li;
      bf[n] = *(const f16x8*)(Bs + row * 64 + (((s * 4 + lg) ^ (row & 7)) * 8));
    }
    __builtin_amdgcn_s_setprio(1);
#pragma unroll
    for (int m = 0; m < 4; ++m)
#pragma unroll
      for (int n = 0; n < 4; ++n)
        acc[m][n] = MFMA16(af[m], bf[n], acc[m][n]);
    __builtin_amdgcn_s_setprio(0);
  }

  int rb = qtile * 128 + wr * 64, cb = ktile * 128 + wc * 64;
#pragma unroll
  for (int m = 0; m < 4; ++m)
#pragma unroll
    for (int r = 0; r < 4; ++r) {
      int qr = rb + m * 16 + lg * 4 + r;
      float ri = mlb[bh * SS + qr];
      float* wb = wts + ((bh * SS + qr) * (size_t)SS) + cb;
#pragma unroll
      for (int n = 0; n < 4; ++n)
        wb[n * 16 + li] = exp2f(acc[m][n][r]) * ri;
    }
}

// ---------------- K3: output projection ----------------
__global__ __launch_bounds__(256) void k_gemm_o(
    const _Float16* __restrict__ attnb, const _Float16* __restrict__ wob,
    const float* __restrict__ bo, float* __restrict__ outp) {
  __shared__ _Float16 As[8192], Bs[8192];
  f32x4 acc[4][4] = {};
  gemm_core(attnb, wob, blockIdx.y, blockIdx.x, As, Bs, acc);

  int t = threadIdx.x, l = t & 63, w = t >> 6, wr = w >> 1, wc = w & 1, li = l & 15, lg = l >> 4;
  int rb = blockIdx.y * 128 + wr * 64, cb = blockIdx.x * 128 + wc * 64;
#pragma unroll
  for (int n = 0; n < 4; ++n) {
    int col = cb + n * 16 + li;
    float bsv = bo[col];
#pragma unroll
    for (int m = 0; m < 4; ++m)
#pragma unroll
      for (int r = 0; r < 4; ++r) {
        int row = rb + m * 16 + lg * 4 + r;
        outp[(size_t)row * DD + col] = acc[m][n][r] + bsv;
      }
  }
}

extern "C" void kernel_launch(void* const* d_in, const int* in_sizes, int n_in,
                              void* d_out, int out_size, void* d_ws, size_t ws_size,
                              hipStream_t stream) {
  const float* x  = (const float*)d_in[0];
  const float* Wq = (const float*)d_in[1];
  const float* bq = (const float*)d_in[2];
  const float* Wk = (const float*)d_in[3];
  const float* bk = (const float*)d_in[4];
  const float* Wv = (const float*)d_in[5];
  const float* bv = (const float*)d_in[6];
  const float* Wo = (const float*)d_in[7];
  const float* bo = (const float*)d_in[8];

  _Float16* ws   = (_Float16*)d_ws;
  _Float16* xb   = ws;
  _Float16* wqb  = ws + 4194304;
  _Float16* wkb  = ws + 5242880;
  _Float16* wvb  = ws + 6291456;
  _Float16* wob  = ws + 7340032;
  _Float16* Qw   = ws + 8388608;
  _Float16* Kw   = ws + 12582912;
  _Float16* Vtw  = ws + 16777216;
  _Float16* attnb= ws + 20971520;               // ends exactly at 48 MiB
  float* mlb = (float*)(ws + 4194304);          // overlays wqb (dead after qkv)

  float* outp = (float*)d_out;                  // [2,2048,1024]
  float* wts  = outp + 4194304;                 // [2,16,2048,2048]

  k_convert<<<dim3(8192), dim3(256), 0, stream>>>(x, Wq, Wk, Wv, Wo, ws);
  k_gemm_qkv<<<dim3(8, 32, 3), dim3(256), 0, stream>>>(xb, wqb, wkb, wvb, bq, bk, bv, Qw, Kw, Vtw);
  k_flash<<<dim3(32, 16, 2), dim3(256), 0, stream>>>(Qw, Kw, Vtw, mlb, attnb);
  k_wts<<<dim3(16, 16, 32), dim3(256), 0, stream>>>(Qw, Kw, mlb, wts);
  k_gemm_o<<<dim3(8, 32, 1), dim3(256), 0, stream>>>(attnb, wob, bo, outp);
}

// Round 11
// 267.498 us; speedup vs baseline: 1.2849x; 1.2849x over previous
//
#include <hip/hip_runtime.h>
#include <stdint.h>

#define BB 2
#define SS 2048
#define DD 1024
#define HH 16
#define HDD 64

typedef _Float16 f16x8 __attribute__((ext_vector_type(8)));
typedef _Float16 f16x4 __attribute__((ext_vector_type(4)));
typedef float f32x4 __attribute__((ext_vector_type(4)));

#define MFMA16(a,b,c) __builtin_amdgcn_mfma_f32_16x16x32_f16((a),(b),(c),0,0,0)

__device__ __forceinline__ _Float16 toh(float v) { return (_Float16)v; }

// async global->LDS, 16B per lane; LDS dest is wave-uniform base + lane*16
__device__ __forceinline__ void gll16(const void* g, void* l) {
  __builtin_amdgcn_global_load_lds(
      (const __attribute__((address_space(1))) unsigned int*)g,
      (__attribute__((address_space(3))) unsigned int*)l, 16, 0, 0);
}

// ---------------- ws layout (f16 elements) — stays under 48 MiB ----------------
//   xb @0 (4194304) | wqb @4194304 | wkb @5242880 | wvb @6291456 | wob @7340032
//   Qw @8388608 [B,H,S,64] (pre-scaled 0.125*log2e) | Kw @12582912 | Vtw @16777216 [B,H,64,S]
//   attnb @20971520 [B,S,D]   (ends exactly at 25165824 f16 = 48 MiB)
//   mlb (f32, 65536) overlays wqb @4194304 (dead after k_gemm_qkv): rinv per row
__global__ __launch_bounds__(256) void k_convert(
    const float* __restrict__ x, const float* __restrict__ Wq, const float* __restrict__ Wk,
    const float* __restrict__ Wv, const float* __restrict__ Wo, _Float16* __restrict__ ws) {
  int i = blockIdx.x * 256 + threadIdx.x;
  const float4* src; _Float16* dst; int idx;
  if (i < 1048576) { src = (const float4*)x; dst = ws; idx = i; }
  else {
    int j = i - 1048576;
    int wsel = j >> 18;
    idx = j & 262143;
    src = (const float4*)(wsel == 0 ? Wq : wsel == 1 ? Wk : wsel == 2 ? Wv : Wo);
    dst = ws + 4194304 + (size_t)wsel * 1048576;
  }
  float4 f = src[idx];
  f16x4 o = { toh(f.x), toh(f.y), toh(f.z), toh(f.w) };
  *(f16x4*)(dst + (size_t)idx * 4) = o;
}

// ---------------- shared GEMM core: C[128x128] = A[128xK] * W[128xK]^T, K=1024 ----------
__device__ __forceinline__ void stage2(const _Float16* g, _Float16* lds, int t) {
#pragma unroll
  for (int i = 0; i < 2; ++i) {
    const _Float16* src = g + (size_t)(i * 64 + (t >> 2)) * 1024 + (t & 3) * 8;
    gll16(src, lds + i * 2048 + t * 8);
  }
}

__device__ __forceinline__ void gemm_core(const _Float16* __restrict__ A,
                                          const _Float16* __restrict__ W,
                                          int bm, int bn, _Float16* As, _Float16* Bs,
                                          f32x4 (&acc)[4][4]) {
  const int t = threadIdx.x;
  const int l = t & 63, w = t >> 6;
  const int wr = w >> 1, wc = w & 1, li = l & 15, lg = l >> 4;
  const _Float16* Abase = A + (size_t)bm * 128 * 1024;
  const _Float16* Wbase = W + (size_t)bn * 128 * 1024;

  stage2(Abase, As, t);
  stage2(Wbase, Bs, t);
  int cur = 0;
  for (int kt = 0; kt < 32; ++kt) {
    __syncthreads();
    if (kt < 31) {
      stage2(Abase + (kt + 1) * 32, As + (cur ^ 1) * 4096, t);
      stage2(Wbase + (kt + 1) * 32, Bs + (cur ^ 1) * 4096, t);
    }
    const _Float16* Ab = As + cur * 4096;
    const _Float16* Bb = Bs + cur * 4096;
    f16x8 af[4], bfr[4];
#pragma unroll
    for (int m = 0; m < 4; ++m)
      af[m] = *(const f16x8*)(Ab + (wr * 64 + m * 16 + li) * 32 + lg * 8);
#pragma unroll
    for (int n = 0; n < 4; ++n)
      bfr[n] = *(const f16x8*)(Bb + (wc * 64 + n * 16 + li) * 32 + lg * 8);
    __builtin_amdgcn_s_setprio(1);
#pragma unroll
    for (int m = 0; m < 4; ++m)
#pragma unroll
      for (int n = 0; n < 4; ++n)
        acc[m][n] = MFMA16(af[m], bfr[n], acc[m][n]);
    __builtin_amdgcn_s_setprio(0);
    cur ^= 1;
  }
}

// ---------------- K1: fused QKV projection ----------------
__global__ __launch_bounds__(256) void k_gemm_qkv(
    const _Float16* __restrict__ xb, const _Float16* __restrict__ wqb,
    const _Float16* __restrict__ wkb, const _Float16* __restrict__ wvb,
    const float* __restrict__ bq, const float* __restrict__ bk, const float* __restrict__ bv,
    _Float16* __restrict__ Qw, _Float16* __restrict__ Kw, _Float16* __restrict__ Vtw) {
  int mode = blockIdx.z;
  const _Float16* W = mode == 0 ? wqb : mode == 1 ? wkb : wvb;
  const float* bias = mode == 0 ? bq : mode == 1 ? bk : bv;
  __shared__ _Float16 As[8192], Bs[8192];
  f32x4 acc[4][4] = {};
  gemm_core(xb, W, blockIdx.y, blockIdx.x, As, Bs, acc);

  int t = threadIdx.x, l = t & 63, w = t >> 6, wr = w >> 1, wc = w & 1, li = l & 15, lg = l >> 4;
  int rb = blockIdx.y * 128 + wr * 64, cb = blockIdx.x * 128 + wc * 64;
  // fold 1/sqrt(HD) and log2(e) into Q so softmax exp becomes exp2
  float scale = (mode == 0) ? 0.125f * 1.4426950408889634f : 1.0f;
#pragma unroll
  for (int n = 0; n < 4; ++n) {
    int col = cb + n * 16 + li;
    float bsv = bias[col];
    int hh = col >> 6, hd = col & 63;
#pragma unroll
    for (int m = 0; m < 4; ++m)
#pragma unroll
      for (int r = 0; r < 4; ++r) {
        int row = rb + m * 16 + lg * 4 + r;
        int bb = row >> 11, ssi = row & 2047;
        float val = (acc[m][n][r] + bsv) * scale;
        if (mode == 0)
          Qw[((size_t)(bb * HH + hh) * SS + ssi) * HDD + hd] = toh(val);
        else if (mode == 1)
          Kw[((size_t)(bb * HH + hh) * SS + ssi) * HDD + hd] = toh(val);
        else
          Vtw[((size_t)(bb * HH + hh) * HDD + hd) * SS + ssi] = toh(val);
      }
  }
}

// ---------------- K2a: flash pass — rinv and attnb ----------------
// R7 skeleton, geometry change only: 8 waves/block (512 thr), 16 q-rows/wave.
// Per-wave code identical to the proven R3/R7 16-row loop (~60 VGPR). LDS 50KB
// -> 2 blocks/CU -> 16 waves/CU (4/SIMD): 2x TLP at same per-CU staging traffic.
__global__ __launch_bounds__(512, 4) void k_flash(
    const _Float16* __restrict__ Qw, const _Float16* __restrict__ Kw,
    const _Float16* __restrict__ Vtw, float* __restrict__ mlb, _Float16* __restrict__ attnb) {
  int qb = blockIdx.x;            // 0..15 (128 rows per block, 16 per wave)
  int h = blockIdx.y, b = blockIdx.z;
  int t = threadIdx.x, l = t & 63, w = t >> 6;   // w = 0..7
  int li = l & 15, lg = l >> 4;
  size_t bh = (size_t)(b * HH + h);
  const _Float16* Qh = Qw + bh * SS * HDD;
  const _Float16* Kh = Kw + bh * SS * HDD;
  const _Float16* Vh = Vtw + bh * HDD * SS;
  int qrow = qb * 128 + w * 16;

  __shared__ _Float16 Kbuf[2][4096];
  __shared__ _Float16 Vbuf[2][4096];
  __shared__ _Float16 Wl[8][16][72];   // per-wave P transpose (+8 pad)

  f16x8 aq0 = *(const f16x8*)&Qh[(size_t)(qrow + li) * HDD + lg * 8];
  f16x8 aq1 = *(const f16x8*)&Qh[(size_t)(qrow + li) * HDD + 32 + lg * 8];

  const f32x4 fzero = {0.f, 0.f, 0.f, 0.f};
  f32x4 oacc[4] = {fzero, fzero, fzero, fzero};
  float lsum[4] = {0.f, 0.f, 0.f, 0.f};

  // stage K/V tile kt into buffer sel; 512 threads -> one gll16 each per buffer
  auto STAGE = [&](int kt, int sel) {
    int kb = kt * 64;
    int row = t >> 3, cc = (t & 7) ^ (row & 7);
    gll16(Kh + (size_t)(kb + row) * HDD + cc * 8, (void*)&Kbuf[sel][t * 8]);
    gll16(Vh + (size_t)row * SS + kb + cc * 8, (void*)&Vbuf[sel][t * 8]);
  };

  STAGE(0, 0);
  __syncthreads();
  int cur = 0;
  for (int kt = 0; kt < 32; ++kt) {
    if (kt < 31) STAGE(kt + 1, cur ^ 1);
    const _Float16* Kb = Kbuf[cur];
    f32x4 sf[4];
    __builtin_amdgcn_s_setprio(1);
#pragma unroll
    for (int f = 0; f < 4; ++f) {
      int row = f * 16 + li;
      f16x8 k0 = *(const f16x8*)(Kb + row * 64 + ((lg ^ (row & 7)) * 8));
      f16x8 k1 = *(const f16x8*)(Kb + row * 64 + (((lg + 4) ^ (row & 7)) * 8));
      f32x4 a = MFMA16(aq0, k0, fzero);
      sf[f] = MFMA16(aq1, k1, a);
    }
    __builtin_amdgcn_s_setprio(0);
#pragma unroll
    for (int f = 0; f < 4; ++f)
#pragma unroll
      for (int r = 0; r < 4; ++r) {
        float p = exp2f(sf[f][r]);
        lsum[r] += p;
        Wl[w][lg * 4 + r][f * 16 + li] = toh(p);
      }
    // PV: A = P (per-wave LDS transpose; lgkmcnt orders within the wave)
    f16x8 aw0 = *(const f16x8*)&Wl[w][li][lg * 8];
    f16x8 aw1 = *(const f16x8*)&Wl[w][li][32 + lg * 8];
    const _Float16* Vb = Vbuf[cur];
    __builtin_amdgcn_s_setprio(1);
#pragma unroll
    for (int n = 0; n < 4; ++n) {
      int row = n * 16 + li;
      f16x8 v0 = *(const f16x8*)(Vb + row * 64 + ((lg ^ (row & 7)) * 8));
      f16x8 v1 = *(const f16x8*)(Vb + row * 64 + (((lg + 4) ^ (row & 7)) * 8));
      oacc[n] = MFMA16(aw0, v0, oacc[n]);
      oacc[n] = MFMA16(aw1, v1, oacc[n]);
    }
    __builtin_amdgcn_s_setprio(0);
    __syncthreads();
    cur ^= 1;
  }

  // deferred row-sum reduce (within 16-lane groups)
#pragma unroll
  for (int d = 1; d < 16; d <<= 1)
#pragma unroll
    for (int r = 0; r < 4; ++r) lsum[r] += __shfl_xor(lsum[r], d);
  float rinv[4];
#pragma unroll
  for (int r = 0; r < 4; ++r) rinv[r] = 1.0f / lsum[r];

#pragma unroll
  for (int n = 0; n < 4; ++n)
#pragma unroll
    for (int r = 0; r < 4; ++r) {
      int q = qrow + lg * 4 + r;
      attnb[((size_t)b * SS + q) * DD + h * 64 + n * 16 + li] = toh(oacc[n][r] * rinv[r]);
    }
  if (li == 0) {
#pragma unroll
    for (int r = 0; r < 4; ++r) {
      int q = qrow + lg * 4 + r;
      mlb[bh * SS + q] = rinv[r];
    }
  }
}

// ---------------- K2b: weights writer — independent 128x128 score tiles ----------------
__global__ __launch_bounds__(256) void k_wts(
    const _Float16* __restrict__ Qw, const _Float16* __restrict__ Kw,
    const float* __restrict__ mlb, float* __restrict__ wts) {
  int ktile = blockIdx.x, qtile = blockIdx.y;
  size_t bh = blockIdx.z;
  const _Float16* Qh = Qw + bh * SS * HDD;
  const _Float16* Kh = Kw + bh * SS * HDD;
  __shared__ _Float16 As[8192], Bs[8192];   // [128 rows][64], src-swizzled
  int t = threadIdx.x, l = t & 63, w = t >> 6, wr = w >> 1, wc = w & 1, li = l & 15, lg = l >> 4;

#pragma unroll
  for (int c4 = 0; c4 < 4; ++c4) {
    int s = c4 * 256 + t;
    int row = s >> 3, cc = (s & 7) ^ (row & 7);
    gll16(Qh + (size_t)(qtile * 128 + row) * HDD + cc * 8, (void*)&As[s * 8]);
    gll16(Kh + (size_t)(ktile * 128 + row) * HDD + cc * 8, (void*)&Bs[s * 8]);
  }
  __syncthreads();

  f32x4 acc[4][4] = {};
#pragma unroll
  for (int s = 0; s < 2; ++s) {
    f16x8 af[4], bf[4];
#pragma unroll
    for (int m = 0; m < 4; ++m) {
      int row = wr * 64 + m * 16 + li;
      af[m] = *(const f16x8*)(As + row * 64 + (((s * 4 + lg) ^ (row & 7)) * 8));
    }
#pragma unroll
    for (int n = 0; n < 4; ++n) {
      int row = wc * 64 + n * 16 + li;
      bf[n] = *(const f16x8*)(Bs + row * 64 + (((s * 4 + lg) ^ (row & 7)) * 8));
    }
    __builtin_amdgcn_s_setprio(1);
#pragma unroll
    for (int m = 0; m < 4; ++m)
#pragma unroll
      for (int n = 0; n < 4; ++n)
        acc[m][n] = MFMA16(af[m], bf[n], acc[m][n]);
    __builtin_amdgcn_s_setprio(0);
  }

  int rb = qtile * 128 + wr * 64, cb = ktile * 128 + wc * 64;
#pragma unroll
  for (int m = 0; m < 4; ++m)
#pragma unroll
    for (int r = 0; r < 4; ++r) {
      int qr = rb + m * 16 + lg * 4 + r;
      float ri = mlb[bh * SS + qr];
      float* wb = wts + ((bh * SS + qr) * (size_t)SS) + cb;
#pragma unroll
      for (int n = 0; n < 4; ++n)
        wb[n * 16 + li] = exp2f(acc[m][n][r]) * ri;
    }
}

// ---------------- K3: output projection ----------------
__global__ __launch_bounds__(256) void k_gemm_o(
    const _Float16* __restrict__ attnb, const _Float16* __restrict__ wob,
    const float* __restrict__ bo, float* __restrict__ outp) {
  __shared__ _Float16 As[8192], Bs[8192];
  f32x4 acc[4][4] = {};
  gemm_core(attnb, wob, blockIdx.y, blockIdx.x, As, Bs, acc);

  int t = threadIdx.x, l = t & 63, w = t >> 6, wr = w >> 1, wc = w & 1, li = l & 15, lg = l >> 4;
  int rb = blockIdx.y * 128 + wr * 64, cb = blockIdx.x * 128 + wc * 64;
#pragma unroll
  for (int n = 0; n < 4; ++n) {
    int col = cb + n * 16 + li;
    float bsv = bo[col];
#pragma unroll
    for (int m = 0; m < 4; ++m)
#pragma unroll
      for (int r = 0; r < 4; ++r) {
        int row = rb + m * 16 + lg * 4 + r;
        outp[(size_t)row * DD + col] = acc[m][n][r] + bsv;
      }
  }
}

extern "C" void kernel_launch(void* const* d_in, const int* in_sizes, int n_in,
                              void* d_out, int out_size, void* d_ws, size_t ws_size,
                              hipStream_t stream) {
  const float* x  = (const float*)d_in[0];
  const float* Wq = (const float*)d_in[1];
  const float* bq = (const float*)d_in[2];
  const float* Wk = (const float*)d_in[3];
  const float* bk = (const float*)d_in[4];
  const float* Wv = (const float*)d_in[5];
  const float* bv = (const float*)d_in[6];
  const float* Wo = (const float*)d_in[7];
  const float* bo = (const float*)d_in[8];

  _Float16* ws   = (_Float16*)d_ws;
  _Float16* xb   = ws;
  _Float16* wqb  = ws + 4194304;
  _Float16* wkb  = ws + 5242880;
  _Float16* wvb  = ws + 6291456;
  _Float16* wob  = ws + 7340032;
  _Float16* Qw   = ws + 8388608;
  _Float16* Kw   = ws + 12582912;
  _Float16* Vtw  = ws + 16777216;
  _Float16* attnb= ws + 20971520;               // ends exactly at 48 MiB
  float* mlb = (float*)(ws + 4194304);          // overlays wqb (dead after qkv)

  float* outp = (float*)d_out;                  // [2,2048,1024]
  float* wts  = outp + 4194304;                 // [2,16,2048,2048]

  k_convert<<<dim3(8192), dim3(256), 0, stream>>>(x, Wq, Wk, Wv, Wo, ws);
  k_gemm_qkv<<<dim3(8, 32, 3), dim3(256), 0, stream>>>(xb, wqb, wkb, wvb, bq, bk, bv, Qw, Kw, Vtw);
  k_flash<<<dim3(16, 16, 2), dim3(512), 0, stream>>>(Qw, Kw, Vtw, mlb, attnb);
  k_wts<<<dim3(16, 16, 32), dim3(256), 0, stream>>>(Qw, Kw, mlb, wts);
  k_gemm_o<<<dim3(8, 32, 1), dim3(256), 0, stream>>>(attnb, wob, bo, outp);
}

// Round 12
// 263.118 us; speedup vs baseline: 1.3062x; 1.0166x over previous
//
#include <hip/hip_runtime.h>
#include <stdint.h>

#define BB 2
#define SS 2048
#define DD 1024
#define HH 16
#define HDD 64

typedef _Float16 f16x8 __attribute__((ext_vector_type(8)));
typedef _Float16 f16x4 __attribute__((ext_vector_type(4)));
typedef float f32x4 __attribute__((ext_vector_type(4)));

#define MFMA16(a,b,c) __builtin_amdgcn_mfma_f32_16x16x32_f16((a),(b),(c),0,0,0)

__device__ __forceinline__ _Float16 toh(float v) { return (_Float16)v; }

// async global->LDS, 16B per lane; LDS dest is wave-uniform base + lane*16
__device__ __forceinline__ void gll16(const void* g, void* l) {
  __builtin_amdgcn_global_load_lds(
      (const __attribute__((address_space(1))) unsigned int*)g,
      (__attribute__((address_space(3))) unsigned int*)l, 16, 0, 0);
}

// ---------------- ws layout (f16 elements) — stays under 48 MiB ----------------
//   xb @0 (4194304) | wqb @4194304 | wkb @5242880 | wvb @6291456 | wob @7340032
//   Qw @8388608 [B,H,S,64] (pre-scaled 0.125*log2e) | Kw @12582912 | Vtw @16777216 [B,H,64,S]
//   attnb @20971520 [B,S,D]   (ends exactly at 25165824 f16 = 48 MiB)
//   mlb (f32, 65536) overlays wqb @4194304 (dead after k_gemm_qkv): rinv per row
__global__ __launch_bounds__(256) void k_convert(
    const float* __restrict__ x, const float* __restrict__ Wq, const float* __restrict__ Wk,
    const float* __restrict__ Wv, const float* __restrict__ Wo, _Float16* __restrict__ ws) {
  int i = blockIdx.x * 256 + threadIdx.x;
  const float4* src; _Float16* dst; int idx;
  if (i < 1048576) { src = (const float4*)x; dst = ws; idx = i; }
  else {
    int j = i - 1048576;
    int wsel = j >> 18;
    idx = j & 262143;
    src = (const float4*)(wsel == 0 ? Wq : wsel == 1 ? Wk : wsel == 2 ? Wv : Wo);
    dst = ws + 4194304 + (size_t)wsel * 1048576;
  }
  float4 f = src[idx];
  f16x4 o = { toh(f.x), toh(f.y), toh(f.z), toh(f.w) };
  *(f16x4*)(dst + (size_t)idx * 4) = o;
}

// ---------------- shared GEMM core: C[128x128] = A[128xK] * W[128xK]^T, K=1024 ----------
__device__ __forceinline__ void stage2(const _Float16* g, _Float16* lds, int t) {
#pragma unroll
  for (int i = 0; i < 2; ++i) {
    const _Float16* src = g + (size_t)(i * 64 + (t >> 2)) * 1024 + (t & 3) * 8;
    gll16(src, lds + i * 2048 + t * 8);
  }
}

__device__ __forceinline__ void gemm_core(const _Float16* __restrict__ A,
                                          const _Float16* __restrict__ W,
                                          int bm, int bn, _Float16* As, _Float16* Bs,
                                          f32x4 (&acc)[4][4]) {
  const int t = threadIdx.x;
  const int l = t & 63, w = t >> 6;
  const int wr = w >> 1, wc = w & 1, li = l & 15, lg = l >> 4;
  const _Float16* Abase = A + (size_t)bm * 128 * 1024;
  const _Float16* Wbase = W + (size_t)bn * 128 * 1024;

  stage2(Abase, As, t);
  stage2(Wbase, Bs, t);
  int cur = 0;
  for (int kt = 0; kt < 32; ++kt) {
    __syncthreads();
    if (kt < 31) {
      stage2(Abase + (kt + 1) * 32, As + (cur ^ 1) * 4096, t);
      stage2(Wbase + (kt + 1) * 32, Bs + (cur ^ 1) * 4096, t);
    }
    const _Float16* Ab = As + cur * 4096;
    const _Float16* Bb = Bs + cur * 4096;
    f16x8 af[4], bfr[4];
#pragma unroll
    for (int m = 0; m < 4; ++m)
      af[m] = *(const f16x8*)(Ab + (wr * 64 + m * 16 + li) * 32 + lg * 8);
#pragma unroll
    for (int n = 0; n < 4; ++n)
      bfr[n] = *(const f16x8*)(Bb + (wc * 64 + n * 16 + li) * 32 + lg * 8);
    __builtin_amdgcn_s_setprio(1);
#pragma unroll
    for (int m = 0; m < 4; ++m)
#pragma unroll
      for (int n = 0; n < 4; ++n)
        acc[m][n] = MFMA16(af[m], bfr[n], acc[m][n]);
    __builtin_amdgcn_s_setprio(0);
    cur ^= 1;
  }
}

// ---------------- K1: fused QKV projection ----------------
__global__ __launch_bounds__(256) void k_gemm_qkv(
    const _Float16* __restrict__ xb, const _Float16* __restrict__ wqb,
    const _Float16* __restrict__ wkb, const _Float16* __restrict__ wvb,
    const float* __restrict__ bq, const float* __restrict__ bk, const float* __restrict__ bv,
    _Float16* __restrict__ Qw, _Float16* __restrict__ Kw, _Float16* __restrict__ Vtw) {
  int mode = blockIdx.z;
  const _Float16* W = mode == 0 ? wqb : mode == 1 ? wkb : wvb;
  const float* bias = mode == 0 ? bq : mode == 1 ? bk : bv;
  __shared__ _Float16 As[8192], Bs[8192];
  f32x4 acc[4][4] = {};
  gemm_core(xb, W, blockIdx.y, blockIdx.x, As, Bs, acc);

  int t = threadIdx.x, l = t & 63, w = t >> 6, wr = w >> 1, wc = w & 1, li = l & 15, lg = l >> 4;
  int rb = blockIdx.y * 128 + wr * 64, cb = blockIdx.x * 128 + wc * 64;
  // fold 1/sqrt(HD) and log2(e) into Q so softmax exp becomes exp2
  float scale = (mode == 0) ? 0.125f * 1.4426950408889634f : 1.0f;
#pragma unroll
  for (int n = 0; n < 4; ++n) {
    int col = cb + n * 16 + li;
    float bsv = bias[col];
    int hh = col >> 6, hd = col & 63;
#pragma unroll
    for (int m = 0; m < 4; ++m)
#pragma unroll
      for (int r = 0; r < 4; ++r) {
        int row = rb + m * 16 + lg * 4 + r;
        int bb = row >> 11, ssi = row & 2047;
        float val = (acc[m][n][r] + bsv) * scale;
        if (mode == 0)
          Qw[((size_t)(bb * HH + hh) * SS + ssi) * HDD + hd] = toh(val);
        else if (mode == 1)
          Kw[((size_t)(bb * HH + hh) * SS + ssi) * HDD + hd] = toh(val);
        else
          Vtw[((size_t)(bb * HH + hh) * HDD + hd) * SS + ssi] = toh(val);
      }
  }
}

// ---------------- K2a: flash pass — rinv and attnb ----------------
// R11 geometry (8 waves/block, 16 q-rows/wave) + XCD-aware block swizzle:
// each XCD owns 2 heads -> K/V (1 MB) L2-resident per XCD.
__global__ __launch_bounds__(512, 4) void k_flash(
    const _Float16* __restrict__ Qw, const _Float16* __restrict__ Kw,
    const _Float16* __restrict__ Vtw, float* __restrict__ mlb, _Float16* __restrict__ attnb) {
  int lin = blockIdx.x;                       // 512 blocks (512 % 8 == 0)
  int swz = (lin & 7) * 64 + (lin >> 3);      // bijective XCD swizzle
  int bhi = swz >> 4, qb = swz & 15;          // bh 0..31, qb 0..15
  int b = bhi >> 4, h = bhi & 15;
  int t = threadIdx.x, l = t & 63, w = t >> 6;   // w = 0..7
  int li = l & 15, lg = l >> 4;
  size_t bh = (size_t)bhi;
  const _Float16* Qh = Qw + bh * SS * HDD;
  const _Float16* Kh = Kw + bh * SS * HDD;
  const _Float16* Vh = Vtw + bh * HDD * SS;
  int qrow = qb * 128 + w * 16;

  __shared__ _Float16 Kbuf[2][4096];
  __shared__ _Float16 Vbuf[2][4096];
  __shared__ _Float16 Wl[8][16][72];   // per-wave P transpose (+8 pad)

  f16x8 aq0 = *(const f16x8*)&Qh[(size_t)(qrow + li) * HDD + lg * 8];
  f16x8 aq1 = *(const f16x8*)&Qh[(size_t)(qrow + li) * HDD + 32 + lg * 8];

  const f32x4 fzero = {0.f, 0.f, 0.f, 0.f};
  f32x4 oacc[4] = {fzero, fzero, fzero, fzero};
  float lsum[4] = {0.f, 0.f, 0.f, 0.f};

  // stage K/V tile kt into buffer sel; 512 threads -> one gll16 each per buffer
  auto STAGE = [&](int kt, int sel) {
    int kb = kt * 64;
    int row = t >> 3, cc = (t & 7) ^ (row & 7);
    gll16(Kh + (size_t)(kb + row) * HDD + cc * 8, (void*)&Kbuf[sel][t * 8]);
    gll16(Vh + (size_t)row * SS + kb + cc * 8, (void*)&Vbuf[sel][t * 8]);
  };

  STAGE(0, 0);
  __syncthreads();
  int cur = 0;
  for (int kt = 0; kt < 32; ++kt) {
    if (kt < 31) STAGE(kt + 1, cur ^ 1);
    const _Float16* Kb = Kbuf[cur];
    f32x4 sf[4];
    __builtin_amdgcn_s_setprio(1);
#pragma unroll
    for (int f = 0; f < 4; ++f) {
      int row = f * 16 + li;
      f16x8 k0 = *(const f16x8*)(Kb + row * 64 + ((lg ^ (row & 7)) * 8));
      f16x8 k1 = *(const f16x8*)(Kb + row * 64 + (((lg + 4) ^ (row & 7)) * 8));
      f32x4 a = MFMA16(aq0, k0, fzero);
      sf[f] = MFMA16(aq1, k1, a);
    }
    __builtin_amdgcn_s_setprio(0);
#pragma unroll
    for (int f = 0; f < 4; ++f)
#pragma unroll
      for (int r = 0; r < 4; ++r) {
        float p = exp2f(sf[f][r]);
        lsum[r] += p;
        Wl[w][lg * 4 + r][f * 16 + li] = toh(p);
      }
    // PV: A = P (per-wave LDS transpose; lgkmcnt orders within the wave)
    f16x8 aw0 = *(const f16x8*)&Wl[w][li][lg * 8];
    f16x8 aw1 = *(const f16x8*)&Wl[w][li][32 + lg * 8];
    const _Float16* Vb = Vbuf[cur];
    __builtin_amdgcn_s_setprio(1);
#pragma unroll
    for (int n = 0; n < 4; ++n) {
      int row = n * 16 + li;
      f16x8 v0 = *(const f16x8*)(Vb + row * 64 + ((lg ^ (row & 7)) * 8));
      f16x8 v1 = *(const f16x8*)(Vb + row * 64 + (((lg + 4) ^ (row & 7)) * 8));
      oacc[n] = MFMA16(aw0, v0, oacc[n]);
      oacc[n] = MFMA16(aw1, v1, oacc[n]);
    }
    __builtin_amdgcn_s_setprio(0);
    __syncthreads();
    cur ^= 1;
  }

  // deferred row-sum reduce (within 16-lane groups)
#pragma unroll
  for (int d = 1; d < 16; d <<= 1)
#pragma unroll
    for (int r = 0; r < 4; ++r) lsum[r] += __shfl_xor(lsum[r], d);
  float rinv[4];
#pragma unroll
  for (int r = 0; r < 4; ++r) rinv[r] = 1.0f / lsum[r];

#pragma unroll
  for (int n = 0; n < 4; ++n)
#pragma unroll
    for (int r = 0; r < 4; ++r) {
      int q = qrow + lg * 4 + r;
      attnb[((size_t)b * SS + q) * DD + h * 64 + n * 16 + li] = toh(oacc[n][r] * rinv[r]);
    }
  if (li == 0) {
#pragma unroll
    for (int r = 0; r < 4; ++r) {
      int q = qrow + lg * 4 + r;
      mlb[bh * SS + q] = rinv[r];
    }
  }
}

// ---------------- K2b: weights writer — independent 128x128 score tiles ----------------
// XCD-aware swizzle: each XCD owns 4 heads -> Q/K (2 MB) L2-resident per XCD,
// freeing fetch BW for the 537 MB store stream.
__global__ __launch_bounds__(256) void k_wts(
    const _Float16* __restrict__ Qw, const _Float16* __restrict__ Kw,
    const float* __restrict__ mlb, float* __restrict__ wts) {
  int lin = blockIdx.x;                        // 8192 blocks (8192 % 8 == 0)
  int swz = (lin & 7) * 1024 + (lin >> 3);     // bijective XCD swizzle
  size_t bh = (size_t)(swz >> 8);              // 4 heads per XCD
  int qtile = (swz >> 4) & 15, ktile = swz & 15;
  const _Float16* Qh = Qw + bh * SS * HDD;
  const _Float16* Kh = Kw + bh * SS * HDD;
  __shared__ _Float16 As[8192], Bs[8192];   // [128 rows][64], src-swizzled
  int t = threadIdx.x, l = t & 63, w = t >> 6, wr = w >> 1, wc = w & 1, li = l & 15, lg = l >> 4;

#pragma unroll
  for (int c4 = 0; c4 < 4; ++c4) {
    int s = c4 * 256 + t;
    int row = s >> 3, cc = (s & 7) ^ (row & 7);
    gll16(Qh + (size_t)(qtile * 128 + row) * HDD + cc * 8, (void*)&As[s * 8]);
    gll16(Kh + (size_t)(ktile * 128 + row) * HDD + cc * 8, (void*)&Bs[s * 8]);
  }
  __syncthreads();

  f32x4 acc[4][4] = {};
#pragma unroll
  for (int s = 0; s < 2; ++s) {
    f16x8 af[4], bf[4];
#pragma unroll
    for (int m = 0; m < 4; ++m) {
      int row = wr * 64 + m * 16 + li;
      af[m] = *(const f16x8*)(As + row * 64 + (((s * 4 + lg) ^ (row & 7)) * 8));
    }
#pragma unroll
    for (int n = 0; n < 4; ++n) {
      int row = wc * 64 + n * 16 + li;
      bf[n] = *(const f16x8*)(Bs + row * 64 + (((s * 4 + lg) ^ (row & 7)) * 8));
    }
    __builtin_amdgcn_s_setprio(1);
#pragma unroll
    for (int m = 0; m < 4; ++m)
#pragma unroll
      for (int n = 0; n < 4; ++n)
        acc[m][n] = MFMA16(af[m], bf[n], acc[m][n]);
    __builtin_amdgcn_s_setprio(0);
  }

  int rb = qtile * 128 + wr * 64, cb = ktile * 128 + wc * 64;
#pragma unroll
  for (int m = 0; m < 4; ++m)
#pragma unroll
    for (int r = 0; r < 4; ++r) {
      int qr = rb + m * 16 + lg * 4 + r;
      float ri = mlb[bh * SS + qr];
      float* wb = wts + ((bh * SS + qr) * (size_t)SS) + cb;
#pragma unroll
      for (int n = 0; n < 4; ++n)
        wb[n * 16 + li] = exp2f(acc[m][n][r]) * ri;
    }
}

// ---------------- K3: output projection ----------------
__global__ __launch_bounds__(256) void k_gemm_o(
    const _Float16* __restrict__ attnb, const _Float16* __restrict__ wob,
    const float* __restrict__ bo, float* __restrict__ outp) {
  __shared__ _Float16 As[8192], Bs[8192];
  f32x4 acc[4][4] = {};
  gemm_core(attnb, wob, blockIdx.y, blockIdx.x, As, Bs, acc);

  int t = threadIdx.x, l = t & 63, w = t >> 6, wr = w >> 1, wc = w & 1, li = l & 15, lg = l >> 4;
  int rb = blockIdx.y * 128 + wr * 64, cb = blockIdx.x * 128 + wc * 64;
#pragma unroll
  for (int n = 0; n < 4; ++n) {
    int col = cb + n * 16 + li;
    float bsv = bo[col];
#pragma unroll
    for (int m = 0; m < 4; ++m)
#pragma unroll
      for (int r = 0; r < 4; ++r) {
        int row = rb + m * 16 + lg * 4 + r;
        outp[(size_t)row * DD + col] = acc[m][n][r] + bsv;
      }
  }
}

extern "C" void kernel_launch(void* const* d_in, const int* in_sizes, int n_in,
                              void* d_out, int out_size, void* d_ws, size_t ws_size,
                              hipStream_t stream) {
  const float* x  = (const float*)d_in[0];
  const float* Wq = (const float*)d_in[1];
  const float* bq = (const float*)d_in[2];
  const float* Wk = (const float*)d_in[3];
  const float* bk = (const float*)d_in[4];
  const float* Wv = (const float*)d_in[5];
  const float* bv = (const float*)d_in[6];
  const float* Wo = (const float*)d_in[7];
  const float* bo = (const float*)d_in[8];

  _Float16* ws   = (_Float16*)d_ws;
  _Float16* xb   = ws;
  _Float16* wqb  = ws + 4194304;
  _Float16* wkb  = ws + 5242880;
  _Float16* wvb  = ws + 6291456;
  _Float16* wob  = ws + 7340032;
  _Float16* Qw   = ws + 8388608;
  _Float16* Kw   = ws + 12582912;
  _Float16* Vtw  = ws + 16777216;
  _Float16* attnb= ws + 20971520;               // ends exactly at 48 MiB
  float* mlb = (float*)(ws + 4194304);          // overlays wqb (dead after qkv)

  float* outp = (float*)d_out;                  // [2,2048,1024]
  float* wts  = outp + 4194304;                 // [2,16,2048,2048]

  k_convert<<<dim3(8192), dim3(256), 0, stream>>>(x, Wq, Wk, Wv, Wo, ws);
  k_gemm_qkv<<<dim3(8, 32, 3), dim3(256), 0, stream>>>(xb, wqb, wkb, wvb, bq, bk, bv, Qw, Kw, Vtw);
  k_flash<<<dim3(512), dim3(512), 0, stream>>>(Qw, Kw, Vtw, mlb, attnb);
  k_wts<<<dim3(8192), dim3(256), 0, stream>>>(Qw, Kw, mlb, wts);
  k_gemm_o<<<dim3(8, 32, 1), dim3(256), 0, stream>>>(attnb, wob, bo, outp);
}

// Round 13
// 252.672 us; speedup vs baseline: 1.3602x; 1.0413x over previous
//
#include <hip/hip_runtime.h>
#include <stdint.h>

#define BB 2
#define SS 2048
#define DD 1024
#define HH 16
#define HDD 64

typedef _Float16 f16x8 __attribute__((ext_vector_type(8)));
typedef _Float16 f16x4 __attribute__((ext_vector_type(4)));
typedef float f32x4 __attribute__((ext_vector_type(4)));

#define MFMA16(a,b,c) __builtin_amdgcn_mfma_f32_16x16x32_f16((a),(b),(c),0,0,0)

__device__ __forceinline__ _Float16 toh(float v) { return (_Float16)v; }

// async global->LDS, 16B per lane; LDS dest is wave-uniform base + lane*16
__device__ __forceinline__ void gll16(const void* g, void* l) {
  __builtin_amdgcn_global_load_lds(
      (const __attribute__((address_space(1))) unsigned int*)g,
      (__attribute__((address_space(3))) unsigned int*)l, 16, 0, 0);
}

// ---------------- ws layout (f16 elements) — stays under 48 MiB ----------------
//   xb @0 (4194304) | wqb @4194304 | wkb @5242880 | wvb @6291456 | wob @7340032
//   Qw @8388608 [B,H,S,64] (pre-scaled 0.125*log2e) | Kw @12582912 | Vtw @16777216 [B,H,64,S]
//   attnb @20971520 [B,S,D]   (ends exactly at 25165824 f16 = 48 MiB)
//   mlb (f32, 65536) overlays wqb @4194304 (dead after k_gemm_qkv): rinv per row
__global__ __launch_bounds__(256) void k_convert(
    const float* __restrict__ x, const float* __restrict__ Wq, const float* __restrict__ Wk,
    const float* __restrict__ Wv, const float* __restrict__ Wo, _Float16* __restrict__ ws) {
  int i = blockIdx.x * 256 + threadIdx.x;
  const float4* src; _Float16* dst; int idx;
  if (i < 1048576) { src = (const float4*)x; dst = ws; idx = i; }
  else {
    int j = i - 1048576;
    int wsel = j >> 18;
    idx = j & 262143;
    src = (const float4*)(wsel == 0 ? Wq : wsel == 1 ? Wk : wsel == 2 ? Wv : Wo);
    dst = ws + 4194304 + (size_t)wsel * 1048576;
  }
  float4 f = src[idx];
  f16x4 o = { toh(f.x), toh(f.y), toh(f.z), toh(f.w) };
  *(f16x4*)(dst + (size_t)idx * 4) = o;
}

// ---------------- shared GEMM core: C[128x128] = A[128xK] * W[128xK]^T, K=1024 ----------
__device__ __forceinline__ void stage2(const _Float16* g, _Float16* lds, int t) {
#pragma unroll
  for (int i = 0; i < 2; ++i) {
    const _Float16* src = g + (size_t)(i * 64 + (t >> 2)) * 1024 + (t & 3) * 8;
    gll16(src, lds + i * 2048 + t * 8);
  }
}

__device__ __forceinline__ void gemm_core(const _Float16* __restrict__ A,
                                          const _Float16* __restrict__ W,
                                          int bm, int bn, _Float16* As, _Float16* Bs,
                                          f32x4 (&acc)[4][4]) {
  const int t = threadIdx.x;
  const int l = t & 63, w = t >> 6;
  const int wr = w >> 1, wc = w & 1, li = l & 15, lg = l >> 4;
  const _Float16* Abase = A + (size_t)bm * 128 * 1024;
  const _Float16* Wbase = W + (size_t)bn * 128 * 1024;

  stage2(Abase, As, t);
  stage2(Wbase, Bs, t);
  int cur = 0;
  for (int kt = 0; kt < 32; ++kt) {
    __syncthreads();
    if (kt < 31) {
      stage2(Abase + (kt + 1) * 32, As + (cur ^ 1) * 4096, t);
      stage2(Wbase + (kt + 1) * 32, Bs + (cur ^ 1) * 4096, t);
    }
    const _Float16* Ab = As + cur * 4096;
    const _Float16* Bb = Bs + cur * 4096;
    f16x8 af[4], bfr[4];
#pragma unroll
    for (int m = 0; m < 4; ++m)
      af[m] = *(const f16x8*)(Ab + (wr * 64 + m * 16 + li) * 32 + lg * 8);
#pragma unroll
    for (int n = 0; n < 4; ++n)
      bfr[n] = *(const f16x8*)(Bb + (wc * 64 + n * 16 + li) * 32 + lg * 8);
    __builtin_amdgcn_s_setprio(1);
#pragma unroll
    for (int m = 0; m < 4; ++m)
#pragma unroll
      for (int n = 0; n < 4; ++n)
        acc[m][n] = MFMA16(af[m], bfr[n], acc[m][n]);
    __builtin_amdgcn_s_setprio(0);
    cur ^= 1;
  }
}

// ---------------- K1: fused QKV projection ----------------
__global__ __launch_bounds__(256) void k_gemm_qkv(
    const _Float16* __restrict__ xb, const _Float16* __restrict__ wqb,
    const _Float16* __restrict__ wkb, const _Float16* __restrict__ wvb,
    const float* __restrict__ bq, const float* __restrict__ bk, const float* __restrict__ bv,
    _Float16* __restrict__ Qw, _Float16* __restrict__ Kw, _Float16* __restrict__ Vtw) {
  int mode = blockIdx.z;
  const _Float16* W = mode == 0 ? wqb : mode == 1 ? wkb : wvb;
  const float* bias = mode == 0 ? bq : mode == 1 ? bk : bv;
  __shared__ _Float16 As[8192], Bs[8192];
  f32x4 acc[4][4] = {};
  gemm_core(xb, W, blockIdx.y, blockIdx.x, As, Bs, acc);

  int t = threadIdx.x, l = t & 63, w = t >> 6, wr = w >> 1, wc = w & 1, li = l & 15, lg = l >> 4;
  int rb = blockIdx.y * 128 + wr * 64, cb = blockIdx.x * 128 + wc * 64;
  // fold 1/sqrt(HD) and log2(e) into Q so softmax exp becomes exp2
  float scale = (mode == 0) ? 0.125f * 1.4426950408889634f : 1.0f;
#pragma unroll
  for (int n = 0; n < 4; ++n) {
    int col = cb + n * 16 + li;
    float bsv = bias[col];
    int hh = col >> 6, hd = col & 63;
#pragma unroll
    for (int m = 0; m < 4; ++m)
#pragma unroll
      for (int r = 0; r < 4; ++r) {
        int row = rb + m * 16 + lg * 4 + r;
        int bb = row >> 11, ssi = row & 2047;
        float val = (acc[m][n][r] + bsv) * scale;
        if (mode == 0)
          Qw[((size_t)(bb * HH + hh) * SS + ssi) * HDD + hd] = toh(val);
        else if (mode == 1)
          Kw[((size_t)(bb * HH + hh) * SS + ssi) * HDD + hd] = toh(val);
        else
          Vtw[((size_t)(bb * HH + hh) * HDD + hd) * SS + ssi] = toh(val);
      }
  }
}

// ---------------- K2a: flash pass — rinv and attnb ----------------
// 8 waves/block (512 thr), 16 q-rows/wave + XCD-aware block swizzle.
__global__ __launch_bounds__(512, 4) void k_flash(
    const _Float16* __restrict__ Qw, const _Float16* __restrict__ Kw,
    const _Float16* __restrict__ Vtw, float* __restrict__ mlb, _Float16* __restrict__ attnb) {
  int lin = blockIdx.x;                       // 512 blocks (512 % 8 == 0)
  int swz = (lin & 7) * 64 + (lin >> 3);      // bijective XCD swizzle
  int bhi = swz >> 4, qb = swz & 15;          // bh 0..31, qb 0..15
  int b = bhi >> 4, h = bhi & 15;
  int t = threadIdx.x, l = t & 63, w = t >> 6;   // w = 0..7
  int li = l & 15, lg = l >> 4;
  size_t bh = (size_t)bhi;
  const _Float16* Qh = Qw + bh * SS * HDD;
  const _Float16* Kh = Kw + bh * SS * HDD;
  const _Float16* Vh = Vtw + bh * HDD * SS;
  int qrow = qb * 128 + w * 16;

  __shared__ _Float16 Kbuf[2][4096];
  __shared__ _Float16 Vbuf[2][4096];
  __shared__ _Float16 Wl[8][16][72];   // per-wave P transpose (+8 pad)

  f16x8 aq0 = *(const f16x8*)&Qh[(size_t)(qrow + li) * HDD + lg * 8];
  f16x8 aq1 = *(const f16x8*)&Qh[(size_t)(qrow + li) * HDD + 32 + lg * 8];

  const f32x4 fzero = {0.f, 0.f, 0.f, 0.f};
  f32x4 oacc[4] = {fzero, fzero, fzero, fzero};
  float lsum[4] = {0.f, 0.f, 0.f, 0.f};

  // stage K/V tile kt into buffer sel; 512 threads -> one gll16 each per buffer
  auto STAGE = [&](int kt, int sel) {
    int kb = kt * 64;
    int row = t >> 3, cc = (t & 7) ^ (row & 7);
    gll16(Kh + (size_t)(kb + row) * HDD + cc * 8, (void*)&Kbuf[sel][t * 8]);
    gll16(Vh + (size_t)row * SS + kb + cc * 8, (void*)&Vbuf[sel][t * 8]);
  };

  STAGE(0, 0);
  __syncthreads();
  int cur = 0;
  for (int kt = 0; kt < 32; ++kt) {
    if (kt < 31) STAGE(kt + 1, cur ^ 1);
    const _Float16* Kb = Kbuf[cur];
    f32x4 sf[4];
    __builtin_amdgcn_s_setprio(1);
#pragma unroll
    for (int f = 0; f < 4; ++f) {
      int row = f * 16 + li;
      f16x8 k0 = *(const f16x8*)(Kb + row * 64 + ((lg ^ (row & 7)) * 8));
      f16x8 k1 = *(const f16x8*)(Kb + row * 64 + (((lg + 4) ^ (row & 7)) * 8));
      f32x4 a = MFMA16(aq0, k0, fzero);
      sf[f] = MFMA16(aq1, k1, a);
    }
    __builtin_amdgcn_s_setprio(0);
#pragma unroll
    for (int f = 0; f < 4; ++f)
#pragma unroll
      for (int r = 0; r < 4; ++r) {
        float p = exp2f(sf[f][r]);
        lsum[r] += p;
        Wl[w][lg * 4 + r][f * 16 + li] = toh(p);
      }
    // PV: A = P (per-wave LDS transpose; lgkmcnt orders within the wave)
    f16x8 aw0 = *(const f16x8*)&Wl[w][li][lg * 8];
    f16x8 aw1 = *(const f16x8*)&Wl[w][li][32 + lg * 8];
    const _Float16* Vb = Vbuf[cur];
    __builtin_amdgcn_s_setprio(1);
#pragma unroll
    for (int n = 0; n < 4; ++n) {
      int row = n * 16 + li;
      f16x8 v0 = *(const f16x8*)(Vb + row * 64 + ((lg ^ (row & 7)) * 8));
      f16x8 v1 = *(const f16x8*)(Vb + row * 64 + (((lg + 4) ^ (row & 7)) * 8));
      oacc[n] = MFMA16(aw0, v0, oacc[n]);
      oacc[n] = MFMA16(aw1, v1, oacc[n]);
    }
    __builtin_amdgcn_s_setprio(0);
    __syncthreads();
    cur ^= 1;
  }

  // deferred row-sum reduce (within 16-lane groups)
#pragma unroll
  for (int d = 1; d < 16; d <<= 1)
#pragma unroll
    for (int r = 0; r < 4; ++r) lsum[r] += __shfl_xor(lsum[r], d);
  float rinv[4];
#pragma unroll
  for (int r = 0; r < 4; ++r) rinv[r] = 1.0f / lsum[r];

#pragma unroll
  for (int n = 0; n < 4; ++n)
#pragma unroll
    for (int r = 0; r < 4; ++r) {
      int q = qrow + lg * 4 + r;
      attnb[((size_t)b * SS + q) * DD + h * 64 + n * 16 + li] = toh(oacc[n][r] * rinv[r]);
    }
  if (li == 0) {
#pragma unroll
    for (int r = 0; r < 4; ++r) {
      int q = qrow + lg * 4 + r;
      mlb[bh * SS + q] = rinv[r];
    }
  }
}

// ---------------- K2b: fused weights-writer + output projection ----------------
// Blocks 0..255: gemm_o path (compute-bound) — dispatched FIRST so its MFMA work
// overlaps the store-backpressure of the 8192 wts blocks that follow.
// Blocks 256..8447: wts path (write-BW-bound), XCD-swizzled.
__global__ __launch_bounds__(256) void k_wts_o(
    const _Float16* __restrict__ Qw, const _Float16* __restrict__ Kw,
    const float* __restrict__ mlb, float* __restrict__ wts,
    const _Float16* __restrict__ attnb, const _Float16* __restrict__ wob,
    const float* __restrict__ bo, float* __restrict__ outp) {
  __shared__ _Float16 As[8192], Bs[8192];
  int t = threadIdx.x, l = t & 63, w = t >> 6, wr = w >> 1, wc = w & 1, li = l & 15, lg = l >> 4;

  if (blockIdx.x < 256) {
    // ---- output projection: out = attnb @ Wo^T + bo ----
    int bn = blockIdx.x & 7, bm = blockIdx.x >> 3;
    f32x4 acc[4][4] = {};
    gemm_core(attnb, wob, bm, bn, As, Bs, acc);
    int rb = bm * 128 + wr * 64, cb = bn * 128 + wc * 64;
#pragma unroll
    for (int n = 0; n < 4; ++n) {
      int col = cb + n * 16 + li;
      float bsv = bo[col];
#pragma unroll
      for (int m = 0; m < 4; ++m)
#pragma unroll
        for (int r = 0; r < 4; ++r) {
          int row = rb + m * 16 + lg * 4 + r;
          outp[(size_t)row * DD + col] = acc[m][n][r] + bsv;
        }
    }
    return;
  }

  // ---- weights path ----
  int lin = blockIdx.x - 256;                  // 8192 blocks (8192 % 8 == 0)
  int swz = (lin & 7) * 1024 + (lin >> 3);     // bijective XCD swizzle
  size_t bh = (size_t)(swz >> 8);              // 4 heads per XCD
  int qtile = (swz >> 4) & 15, ktile = swz & 15;
  const _Float16* Qh = Qw + bh * SS * HDD;
  const _Float16* Kh = Kw + bh * SS * HDD;

#pragma unroll
  for (int c4 = 0; c4 < 4; ++c4) {
    int s = c4 * 256 + t;
    int row = s >> 3, cc = (s & 7) ^ (row & 7);
    gll16(Qh + (size_t)(qtile * 128 + row) * HDD + cc * 8, (void*)&As[s * 8]);
    gll16(Kh + (size_t)(ktile * 128 + row) * HDD + cc * 8, (void*)&Bs[s * 8]);
  }
  __syncthreads();

  f32x4 acc[4][4] = {};
#pragma unroll
  for (int s = 0; s < 2; ++s) {
    f16x8 af[4], bf[4];
#pragma unroll
    for (int m = 0; m < 4; ++m) {
      int row = wr * 64 + m * 16 + li;
      af[m] = *(const f16x8*)(As + row * 64 + (((s * 4 + lg) ^ (row & 7)) * 8));
    }
#pragma unroll
    for (int n = 0; n < 4; ++n) {
      int row = wc * 64 + n * 16 + li;
      bf[n] = *(const f16x8*)(Bs + row * 64 + (((s * 4 + lg) ^ (row & 7)) * 8));
    }
    __builtin_amdgcn_s_setprio(1);
#pragma unroll
    for (int m = 0; m < 4; ++m)
#pragma unroll
      for (int n = 0; n < 4; ++n)
        acc[m][n] = MFMA16(af[m], bf[n], acc[m][n]);
    __builtin_amdgcn_s_setprio(0);
  }

  int rb = qtile * 128 + wr * 64, cb = ktile * 128 + wc * 64;
#pragma unroll
  for (int m = 0; m < 4; ++m)
#pragma unroll
    for (int r = 0; r < 4; ++r) {
      int qr = rb + m * 16 + lg * 4 + r;
      float ri = mlb[bh * SS + qr];
      float* wb = wts + ((bh * SS + qr) * (size_t)SS) + cb;
#pragma unroll
      for (int n = 0; n < 4; ++n)
        wb[n * 16 + li] = exp2f(acc[m][n][r]) * ri;
    }
}

extern "C" void kernel_launch(void* const* d_in, const int* in_sizes, int n_in,
                              void* d_out, int out_size, void* d_ws, size_t ws_size,
                              hipStream_t stream) {
  const float* x  = (const float*)d_in[0];
  const float* Wq = (const float*)d_in[1];
  const float* bq = (const float*)d_in[2];
  const float* Wk = (const float*)d_in[3];
  const float* bk = (const float*)d_in[4];
  const float* Wv = (const float*)d_in[5];
  const float* bv = (const float*)d_in[6];
  const float* Wo = (const float*)d_in[7];
  const float* bo = (const float*)d_in[8];

  _Float16* ws   = (_Float16*)d_ws;
  _Float16* xb   = ws;
  _Float16* wqb  = ws + 4194304;
  _Float16* wkb  = ws + 5242880;
  _Float16* wvb  = ws + 6291456;
  _Float16* wob  = ws + 7340032;
  _Float16* Qw   = ws + 8388608;
  _Float16* Kw   = ws + 12582912;
  _Float16* Vtw  = ws + 16777216;
  _Float16* attnb= ws + 20971520;               // ends exactly at 48 MiB
  float* mlb = (float*)(ws + 4194304);          // overlays wqb (dead after qkv)

  float* outp = (float*)d_out;                  // [2,2048,1024]
  float* wts  = outp + 4194304;                 // [2,16,2048,2048]

  k_convert<<<dim3(8192), dim3(256), 0, stream>>>(x, Wq, Wk, Wv, Wo, ws);
  k_gemm_qkv<<<dim3(8, 32, 3), dim3(256), 0, stream>>>(xb, wqb, wkb, wvb, bq, bk, bv, Qw, Kw, Vtw);
  k_flash<<<dim3(512), dim3(512), 0, stream>>>(Qw, Kw, Vtw, mlb, attnb);
  k_wts_o<<<dim3(8448), dim3(256), 0, stream>>>(Qw, Kw, mlb, wts, attnb, wob, bo, outp);
}